// Round 1
// baseline (2174.827 us; speedup 1.0000x reference)
//
#include <hip/hip_runtime.h>
#include <math.h>

// Problem constants
#define BB 2
#define TT 2048
#define DM 1024
#define NH 16
#define DKK 64
#define MTOT (BB*TT)        // 4096
#define BHN (BB*NH)         // 32

// ---------------------------------------------------------------------------
// GEMM: C = A(MxK) * Bt(NxK)^T, M=4096, N=1024, K=1024, fp32.
// mode 0: A = x row-major [M][K]; C scattered to QKV layout [B,H,T,64]
// mode 1: A gathered from attn_out [B,H,T,64] as logical [B,T,H*64]; C plain [M][N]
// Tile: BM=BN=128, BK=16, 256 threads, 8x8 microtile per thread.
// ---------------------------------------------------------------------------
__global__ __launch_bounds__(256) void gemm_bt_f32(
    const float* __restrict__ A, const float* __restrict__ Bt,
    float* __restrict__ C, int mode)
{
    __shared__ float As[16][128];
    __shared__ float Bs[16][128];

    const int tid = threadIdx.x;
    const int m_base = blockIdx.x * 128;   // 0..31
    const int n_base = blockIdx.y * 128;   // 0..7
    const int ty = tid >> 4, tx = tid & 15;
    const int mo = ty * 8, no = tx * 8;

    float acc[8][8];
#pragma unroll
    for (int i = 0; i < 8; ++i)
#pragma unroll
        for (int j = 0; j < 8; ++j) acc[i][j] = 0.0f;

    for (int k0 = 0; k0 < 1024; k0 += 16) {
        // Load A tile (128x16) and B tile (128x16), transposed into LDS [k][m]
#pragma unroll
        for (int l = 0; l < 2; ++l) {
            int idx = tid + l * 256;       // 0..511 float4 slots
            int row = idx >> 2;            // 0..127
            int kc  = (idx & 3) * 4;       // 0,4,8,12
            float4 va;
            if (mode == 0) {
                int m = m_base + row;
                va = *(const float4*)(A + (size_t)m * 1024 + k0 + kc);
            } else {
                int m = m_base + row;
                int b = m >> 11, t = m & 2047;
                int k = k0 + kc;
                int h = k >> 6, d = k & 63;
                va = *(const float4*)(A + (((size_t)(b * 16 + h)) * 2048 + t) * 64 + d);
            }
            As[kc + 0][row] = va.x; As[kc + 1][row] = va.y;
            As[kc + 2][row] = va.z; As[kc + 3][row] = va.w;

            int nrow = n_base + row;
            float4 vb = *(const float4*)(Bt + (size_t)nrow * 1024 + k0 + kc);
            Bs[kc + 0][row] = vb.x; Bs[kc + 1][row] = vb.y;
            Bs[kc + 2][row] = vb.z; Bs[kc + 3][row] = vb.w;
        }
        __syncthreads();

#pragma unroll
        for (int k = 0; k < 16; ++k) {
            float a[8], b[8];
            *(float4*)(a)     = *(const float4*)&As[k][mo];
            *(float4*)(a + 4) = *(const float4*)&As[k][mo + 4];
            *(float4*)(b)     = *(const float4*)&Bs[k][no];
            *(float4*)(b + 4) = *(const float4*)&Bs[k][no + 4];
#pragma unroll
            for (int i = 0; i < 8; ++i)
#pragma unroll
                for (int j = 0; j < 8; ++j)
                    acc[i][j] = fmaf(a[i], b[j], acc[i][j]);
        }
        __syncthreads();
    }

    // Store
#pragma unroll
    for (int i = 0; i < 8; ++i) {
        int m = m_base + mo + i;
        if (mode == 0) {
            int n = n_base + no;
            int b = m >> 11, t = m & 2047;
            int h = n >> 6, d = n & 63;   // 8-chunk never crosses a head boundary
            float* dst = C + (((size_t)(b * 16 + h)) * 2048 + t) * 64 + d;
            *(float4*)(dst)     = *(const float4*)&acc[i][0];
            *(float4*)(dst + 4) = *(const float4*)&acc[i][4];
        } else {
            float* dst = C + (size_t)m * 1024 + n_base + no;
            *(float4*)(dst)     = *(const float4*)&acc[i][0];
            *(float4*)(dst + 4) = *(const float4*)&acc[i][4];
        }
    }
}

// ---------------------------------------------------------------------------
// Pass 1 of softmax: per (b,h, 64-row q tile), stream over all 2048 k-cols
// computing row max and row sum-exp (online). Scores recomputed in pass 2.
// ---------------------------------------------------------------------------
__global__ __launch_bounds__(256) void rowstats(
    const float* __restrict__ Q, const float* __restrict__ Kmat,
    float* __restrict__ rowmax, float* __restrict__ rowsum)
{
    __shared__ float Qs[64][64];    // [d][r]
    __shared__ float Ks[64][128];   // [d][c]

    const int qt = blockIdx.x;      // 0..31
    const int bh = blockIdx.y;      // 0..31
    const float* Qb = Q + ((size_t)bh * 2048 + qt * 64) * 64;
    const float* Kb = Kmat + (size_t)bh * 2048 * 64;
    const int tid = threadIdx.x;

    // Stage Q tile transposed: 64 rows x 64 d
#pragma unroll
    for (int l = 0; l < 4; ++l) {
        int idx = tid + l * 256;       // float4 index, 1024 total
        int r = idx >> 4;
        int d0 = (idx & 15) * 4;
        float4 v = *(const float4*)(Qb + (size_t)r * 64 + d0);
        Qs[d0 + 0][r] = v.x; Qs[d0 + 1][r] = v.y;
        Qs[d0 + 2][r] = v.z; Qs[d0 + 3][r] = v.w;
    }

    const int ty = tid >> 4, tx = tid & 15;
    const int r0 = ty * 4;
    float mrow[4], lrow[4];
#pragma unroll
    for (int i = 0; i < 4; ++i) { mrow[i] = -INFINITY; lrow[i] = 0.0f; }

    for (int kt = 0; kt < 16; ++kt) {
        __syncthreads();
        // Stage K tile (128 cols) transposed
#pragma unroll
        for (int l = 0; l < 8; ++l) {
            int idx = tid + l * 256;     // 2048 float4
            int c = idx >> 4;
            int d0 = (idx & 15) * 4;
            float4 v = *(const float4*)(Kb + ((size_t)kt * 128 + c) * 64 + d0);
            Ks[d0 + 0][c] = v.x; Ks[d0 + 1][c] = v.y;
            Ks[d0 + 2][c] = v.z; Ks[d0 + 3][c] = v.w;
        }
        __syncthreads();

        float s[4][8];
#pragma unroll
        for (int i = 0; i < 4; ++i)
#pragma unroll
            for (int j = 0; j < 8; ++j) s[i][j] = 0.0f;

        for (int d = 0; d < 64; ++d) {
            float a[4], b[8];
            *(float4*)(a)     = *(const float4*)&Qs[d][r0];
            *(float4*)(b)     = *(const float4*)&Ks[d][tx * 8];
            *(float4*)(b + 4) = *(const float4*)&Ks[d][tx * 8 + 4];
#pragma unroll
            for (int i = 0; i < 4; ++i)
#pragma unroll
                for (int j = 0; j < 8; ++j)
                    s[i][j] = fmaf(a[i], b[j], s[i][j]);
        }

        // Online max/sumexp update (scale 1/sqrt(64) = 0.125)
#pragma unroll
        for (int i = 0; i < 4; ++i) {
            float mx = s[i][0];
#pragma unroll
            for (int j = 1; j < 8; ++j) mx = fmaxf(mx, s[i][j]);
            mx *= 0.125f;
            float mnew = fmaxf(mrow[i], mx);
            float ls = 0.0f;
#pragma unroll
            for (int j = 0; j < 8; ++j) ls += __expf(s[i][j] * 0.125f - mnew);
            lrow[i] = lrow[i] * __expf(mrow[i] - mnew) + ls;
            mrow[i] = mnew;
        }
    }

    // Reduce across the 16 tx-threads sharing the same rows (contiguous lanes)
#pragma unroll
    for (int off = 1; off < 16; off <<= 1) {
#pragma unroll
        for (int i = 0; i < 4; ++i) {
            float mo = __shfl_xor(mrow[i], off);
            float lo = __shfl_xor(lrow[i], off);
            float mn = fmaxf(mrow[i], mo);
            lrow[i] = lrow[i] * __expf(mrow[i] - mn) + lo * __expf(mo - mn);
            mrow[i] = mn;
        }
    }
    if (tx == 0) {
#pragma unroll
        for (int i = 0; i < 4; ++i) {
            int r = qt * 64 + r0 + i;
            rowmax[(size_t)bh * 2048 + r] = mrow[i];
            rowsum[(size_t)bh * 2048 + r] = lrow[i];
        }
    }
}

// ---------------------------------------------------------------------------
// Pass 2: recompute scores per 64x64 tile (same d-summation order as pass 1),
// normalize with (rowmax, rowsum), write attn_weights, and accumulate O = P.V.
// ---------------------------------------------------------------------------
__global__ __launch_bounds__(256) void attn_pv(
    const float* __restrict__ Q, const float* __restrict__ Kmat,
    const float* __restrict__ V,
    const float* __restrict__ rowmax, const float* __restrict__ rowsum,
    float* __restrict__ wout, float* __restrict__ aout)
{
    __shared__ float Qs[64][64];   // [d][r]
    __shared__ float Ks[64][64];   // [d][c]
    __shared__ float Vs[64][64];   // [kk][dd]
    __shared__ float Ps[64][64];   // [kk][r]

    const int qt = blockIdx.x;
    const int bh = blockIdx.y;
    const float* Qb = Q + ((size_t)bh * 2048 + qt * 64) * 64;
    const float* Kb = Kmat + (size_t)bh * 2048 * 64;
    const float* Vb = V + (size_t)bh * 2048 * 64;
    const int tid = threadIdx.x;

#pragma unroll
    for (int l = 0; l < 4; ++l) {
        int idx = tid + l * 256;
        int r = idx >> 4;
        int d0 = (idx & 15) * 4;
        float4 v = *(const float4*)(Qb + (size_t)r * 64 + d0);
        Qs[d0 + 0][r] = v.x; Qs[d0 + 1][r] = v.y;
        Qs[d0 + 2][r] = v.z; Qs[d0 + 3][r] = v.w;
    }

    const int ty = tid >> 4, tx = tid & 15;
    const int r0 = ty * 4, c0 = tx * 4;

    float M[4], Li[4];
#pragma unroll
    for (int i = 0; i < 4; ++i) {
        size_t r = (size_t)bh * 2048 + qt * 64 + r0 + i;
        M[i] = rowmax[r];
        Li[i] = 1.0f / rowsum[r];
    }

    float accO[4][4];
#pragma unroll
    for (int i = 0; i < 4; ++i)
#pragma unroll
        for (int j = 0; j < 4; ++j) accO[i][j] = 0.0f;

    for (int kt = 0; kt < 32; ++kt) {
        __syncthreads();   // protect Ks/Vs/Ps reuse from previous iteration
#pragma unroll
        for (int l = 0; l < 4; ++l) {
            int idx = tid + l * 256;
            int c = idx >> 4;
            int d0 = (idx & 15) * 4;
            float4 kv = *(const float4*)(Kb + ((size_t)kt * 64 + c) * 64 + d0);
            Ks[d0 + 0][c] = kv.x; Ks[d0 + 1][c] = kv.y;
            Ks[d0 + 2][c] = kv.z; Ks[d0 + 3][c] = kv.w;
            float4 vv = *(const float4*)(Vb + ((size_t)kt * 64 + c) * 64 + d0);
            *(float4*)&Vs[c][d0] = vv;
        }
        __syncthreads();

        // Scores 64x64: micro 4x4
        float s[4][4];
#pragma unroll
        for (int i = 0; i < 4; ++i)
#pragma unroll
            for (int j = 0; j < 4; ++j) s[i][j] = 0.0f;

        for (int d = 0; d < 64; ++d) {
            float a[4], b[4];
            *(float4*)(a) = *(const float4*)&Qs[d][r0];
            *(float4*)(b) = *(const float4*)&Ks[d][c0];
#pragma unroll
            for (int i = 0; i < 4; ++i)
#pragma unroll
                for (int j = 0; j < 4; ++j)
                    s[i][j] = fmaf(a[i], b[j], s[i][j]);
        }

        // Normalize, write weights, stash P^T for the PV GEMM
#pragma unroll
        for (int i = 0; i < 4; ++i) {
            float w[4];
#pragma unroll
            for (int j = 0; j < 4; ++j)
                w[j] = __expf(s[i][j] * 0.125f - M[i]) * Li[i];
            size_t off = ((size_t)bh * 2048 + qt * 64 + r0 + i) * 2048
                       + (size_t)kt * 64 + c0;
            *(float4*)(wout + off) = *(const float4*)w;
#pragma unroll
            for (int j = 0; j < 4; ++j) Ps[c0 + j][r0 + i] = w[j];
        }
        __syncthreads();

        // O += P.V : micro 4x4 over (rows r0.., dcols tx*4..)
        for (int kk = 0; kk < 64; ++kk) {
            float p[4], v[4];
            *(float4*)(p) = *(const float4*)&Ps[kk][r0];
            *(float4*)(v) = *(const float4*)&Vs[kk][tx * 4];
#pragma unroll
            for (int i = 0; i < 4; ++i)
#pragma unroll
                for (int j = 0; j < 4; ++j)
                    accO[i][j] = fmaf(p[i], v[j], accO[i][j]);
        }
    }

#pragma unroll
    for (int i = 0; i < 4; ++i) {
        float* dst = aout + ((size_t)bh * 2048 + qt * 64 + r0 + i) * 64 + tx * 4;
        *(float4*)dst = *(const float4*)&accO[i][0];
    }
}

// ---------------------------------------------------------------------------
extern "C" void kernel_launch(void* const* d_in, const int* in_sizes, int n_in,
                              void* d_out, int out_size, void* d_ws, size_t ws_size,
                              hipStream_t stream) {
    const float* x  = (const float*)d_in[0];
    const float* Wq = (const float*)d_in[1];
    const float* Wk = (const float*)d_in[2];
    const float* Wv = (const float*)d_in[3];
    const float* Wo = (const float*)d_in[4];

    float* out0 = (float*)d_out;                       // [2,2048,1024]
    float* out1 = out0 + (size_t)MTOT * DM;            // attn_weights [2,16,2048,2048]

    float* ws   = (float*)d_ws;                        // 64.5 MB used
    float* Qm   = ws;                                  // [B,H,T,64] 4.19M floats
    float* Km   = Qm + (size_t)4194304;
    float* Vm   = Km + (size_t)4194304;
    float* AO   = Vm + (size_t)4194304;                // attn_out [B,H,T,64]
    float* rmax = AO + (size_t)4194304;                // [32*2048]
    float* rsum = rmax + (size_t)65536;

    dim3 blk(256);
    dim3 gg(32, 8);
    gemm_bt_f32<<<gg, blk, 0, stream>>>(x, Wq, Qm, 0);
    gemm_bt_f32<<<gg, blk, 0, stream>>>(x, Wk, Km, 0);
    gemm_bt_f32<<<gg, blk, 0, stream>>>(x, Wv, Vm, 0);

    dim3 ga(32, 32);
    rowstats<<<ga, blk, 0, stream>>>(Qm, Km, rmax, rsum);
    attn_pv<<<ga, blk, 0, stream>>>(Qm, Km, Vm, rmax, rsum, out1, AO);

    gemm_bt_f32<<<gg, blk, 0, stream>>>(AO, Wo, out0, 1);
}